// Round 12
// baseline (167.641 us; speedup 1.0000x reference)
//
#include <hip/hip_runtime.h>
#include <hip/hip_bf16.h>

#define DDIM 2048
#define TTIMES 256
#define NTA 32                // A-steps of 64 k
#define THREADS 1024

typedef __attribute__((ext_vector_type(8))) short short8;
typedef __attribute__((ext_vector_type(4))) float f32x4;

using gvoid = const __attribute__((address_space(1))) void;
using svoid = __attribute__((address_space(3))) void;

__device__ __forceinline__ void gld16(const void* g, void* l) {
    __builtin_amdgcn_global_load_lds((gvoid*)g, (svoid*)l, 16, 0, 0);
}

__device__ __forceinline__ ushort f2bf(float f) {
    union { float f; unsigned int u; } v; v.f = f;
    unsigned int u = v.u;
    unsigned int r = (u + 0x7FFFu + ((u >> 16) & 1u)) >> 16;   // RNE
    return (ushort)r;
}
__device__ __forceinline__ float bf2f(ushort u) {
    union { unsigned int u; float f; } v; v.u = ((unsigned int)u) << 16;
    return v.f;
}
__device__ __forceinline__ short cvt1(float f) {
    union { __hip_bfloat16 h; ushort u; } cv;
    cv.h = __float2bfloat16(f);          // hardware RNE cvt
    return (short)cv.u;
}

// ---------------- normalize org rows -> bf16 o in workspace ----------------
__global__ void norm_rows(const float* __restrict__ org, ushort* __restrict__ obf) {
    const int a   = blockIdx.x;     // time row
    const int tid = threadIdx.x;    // 256 threads
    const float* row = org + (size_t)a * DDIM;
    float4 v0 = ((const float4*)row)[tid * 2];
    float4 v1 = ((const float4*)row)[tid * 2 + 1];
    float s = v0.x*v0.x + v0.y*v0.y + v0.z*v0.z + v0.w*v0.w
            + v1.x*v1.x + v1.y*v1.y + v1.z*v1.z + v1.w*v1.w;
    #pragma unroll
    for (int off = 1; off < 64; off <<= 1) s += __shfl_xor(s, off);
    __shared__ float wsum[4];
    const int lane = tid & 63, w = tid >> 6;
    if (lane == 0) wsum[w] = s;
    __syncthreads();
    const float tot = wsum[0] + wsum[1] + wsum[2] + wsum[3];
    const float scale = 1.0f / fmaxf(sqrtf(tot), 1e-12f);
    union { ushort u[8]; uint4 v; } pk;
    pk.u[0] = f2bf(v0.x * scale); pk.u[1] = f2bf(v0.y * scale);
    pk.u[2] = f2bf(v0.z * scale); pk.u[3] = f2bf(v0.w * scale);
    pk.u[4] = f2bf(v1.x * scale); pk.u[5] = f2bf(v1.y * scale);
    pk.u[6] = f2bf(v1.z * scale); pk.u[7] = f2bf(v1.w * scale);
    ((uint4*)(obf + (size_t)a * DDIM))[tid] = pk.v;
}

// ---- BK_A=64 (256 B runs/row), 2 k=32 substeps, all gload_lds DMA ----
// 1024 thr = 16 waves (4 wm x 4 wn). A: fp32 3-deep 32 KB tiles (2-step lead);
// B: bf16 16 KB per substep, 2-deep (L2-fed, 1-substep lead). LDS 128 KiB ->
// 1 block/CU, 16 waves. Even substep: vmcnt(0) (all drained have >=2-substep
// lead); odd: vmcnt(2) keeps A(T+2) flying. 1 barrier per substep. K-staggered.
__global__ __launch_bounds__(THREADS, 4) void gemm_trace(
    const float* __restrict__ x, const ushort* __restrict__ obf,
    float* __restrict__ part)
{
    __shared__ __align__(16) char Ab[3][32768];   // fp32 A: 128 rows x 64 k
    __shared__ __align__(16) char Bb[2][16384];   // bf16 B: 256 rows x 32 k

    const int tid  = threadIdx.x;
    const int lane = tid & 63;
    const int wid  = tid >> 6;      // 0..15
    const int wm   = wid >> 2;      // 0..3 (32-row group)
    const int wn   = wid & 3;       // 0..3 (64-time group)
    const int rb   = blockIdx.x;    // 0..15 (row block of 128)
    const int d    = blockIdx.y;    // 0..31 (batch)
    const int T0   = (d * 16 + rb) & (NTA - 1);   // A-step stagger phase
#define WT(n) ((T0 + (n)) & (NTA - 1))

    const char* ab = (const char*)(x + (size_t)d * DDIM * DDIM + (size_t)rb * 128 * DDIM);
    const char* bb = (const char*)obf;

    // A staging: 2048 chunks (128 rows x 16); 2 per thread; src pre-swizzled
    const int ac0 = tid,        ar0 = ac0 >> 4, aq0 = ((ac0 & 15) ^ (ar0 & 7)) * 16;
    const int ac1 = tid + 1024, ar1 = ac1 >> 4, aq1 = ((ac1 & 15) ^ (ar1 & 7)) * 16;
    const char* as0 = ab + (size_t)ar0 * (DDIM * 4) + aq0;
    const char* as1 = ab + (size_t)ar1 * (DDIM * 4) + aq1;

    // B staging: 1024 chunks (256 rows x 4); 1 per thread; src pre-swizzled
    const int brw = tid >> 2;
    const char* bsr = bb + (size_t)brw * (DDIM * 2)
                    + (((tid & 3) ^ ((brw >> 1) & 3)) * 16);

#define STAGE_A(T, buf) do {                                  \
    gld16(as0 + (size_t)(T) * 256, &Ab[buf][ac0 * 16]);       \
    gld16(as1 + (size_t)(T) * 256, &Ab[buf][ac1 * 16]);       \
} while (0)
#define STAGE_B(g, buf) do {                                  \
    gld16(bsr + (size_t)(g) * 64, &Bb[buf][tid * 16]);        \
} while (0)

    const int lr = lane & 15;       // row-in-16
    const int lq = lane >> 4;       // k-quarter

    // A fragment offsets: row ra = wm*32 + mi*16 + lr; chunk q = ksub*8+lq*2+j
    int arow[2], arx[2];
    #pragma unroll
    for (int mi = 0; mi < 2; ++mi) {
        const int ra = wm * 32 + mi * 16 + lr;
        arow[mi] = ra * 256;        // byte base
        arx[mi]  = ra & 7;
    }
    // B fragment offsets: row rt = wn*64 + ni*16 + lr; chunk q = lq
    int boff[4];
    #pragma unroll
    for (int ni = 0; ni < 4; ++ni) {
        const int rt = wn * 64 + ni * 16 + lr;
        boff[ni] = rt * 64 + ((lq ^ ((rt >> 1) & 3)) * 16);
    }

    f32x4 acc[2][4];
    #pragma unroll
    for (int mi = 0; mi < 2; ++mi)
        #pragma unroll
        for (int ni = 0; ni < 4; ++ni)
            acc[mi][ni] = (f32x4){0.f, 0.f, 0.f, 0.f};

#define COMPUTE(abuf, ksub, bbuf) do {                                      \
    short8 af[2], bfr[4];                                                   \
    _Pragma("unroll")                                                       \
    for (int mi = 0; mi < 2; ++mi) {                                        \
        const int q0_ = (ksub) * 8 + lq * 2;                                \
        const float4 lo = *(const float4*)                                  \
            &Ab[abuf][arow[mi] + ((q0_)     ^ arx[mi]) * 16];               \
        const float4 hi = *(const float4*)                                  \
            &Ab[abuf][arow[mi] + ((q0_ + 1) ^ arx[mi]) * 16];               \
        short8 a8;                                                          \
        a8[0] = cvt1(lo.x); a8[1] = cvt1(lo.y);                             \
        a8[2] = cvt1(lo.z); a8[3] = cvt1(lo.w);                             \
        a8[4] = cvt1(hi.x); a8[5] = cvt1(hi.y);                             \
        a8[6] = cvt1(hi.z); a8[7] = cvt1(hi.w);                             \
        af[mi] = a8;                                                        \
    }                                                                       \
    _Pragma("unroll")                                                       \
    for (int ni = 0; ni < 4; ++ni)                                          \
        bfr[ni] = *(const short8*)&Bb[bbuf][boff[ni]];                      \
    _Pragma("unroll")                                                       \
    for (int mi = 0; mi < 2; ++mi)                                          \
        _Pragma("unroll")                                                   \
        for (int ni = 0; ni < 4; ++ni)                                      \
            acc[mi][ni] = __builtin_amdgcn_mfma_f32_16x16x32_bf16(          \
                af[mi], bfr[ni], acc[mi][ni], 0, 0, 0);                     \
} while (0)

#define VMW(n) do {                                                         \
    asm volatile("s_waitcnt vmcnt(" #n ")" ::: "memory");                   \
    __builtin_amdgcn_sched_barrier(0); } while (0)
#define SBAR do {                                                           \
    __builtin_amdgcn_sched_barrier(0);                                      \
    asm volatile("s_waitcnt lgkmcnt(0)" ::: "memory");                      \
    __builtin_amdgcn_s_barrier();                                           \
    __builtin_amdgcn_sched_barrier(0); } while (0)

    // ---- prologue: A(0)->0, B(g=0)->buf0, A(1)->1  (queue: 2+1+2) ----
    STAGE_A(WT(0), 0);
    STAGE_B(WT(0) * 2 + 0, 0);
    STAGE_A(WT(1), 1);

    int abf = 0;                   // T % 3
    #pragma unroll 1
    for (int T = 0; T < NTA - 1; ++T) {
        // even substep s = 2T
        VMW(0);                    // drain: A(T+1) (2-sub lead), B(2T) (1-sub)
        SBAR;
        STAGE_B(WT(T) * 2 + 1, 1);           // B for odd substep
        if (T + 2 < NTA) {
            int ab2 = abf + 2; if (ab2 >= 3) ab2 -= 3;
            STAGE_A(WT(T + 2), ab2);
        }
        COMPUTE(abf, 0, 0);
        // odd substep s = 2T+1
        if (T + 2 < NTA) { VMW(2); }         // retire B(2T+1); keep A(T+2)
        else             { VMW(0); }
        SBAR;
        STAGE_B(WT(T + 1) * 2 + 0, 0);       // B for next even substep
        COMPUTE(abf, 1, 1);
        ++abf; if (abf == 3) abf = 0;
    }
    // ---- T = NTA-1 ----
    VMW(0);
    SBAR;
    STAGE_B(WT(NTA - 1) * 2 + 1, 1);
    COMPUTE(abf, 0, 0);
    VMW(0);
    SBAR;
    COMPUTE(abf, 1, 1);
    __syncthreads();

#undef WT
#undef STAGE_A
#undef STAGE_B
#undef COMPUTE
#undef VMW
#undef SBAR

    // ---- fused trace epilogue ----
    // acc[mi][ni][j]: row = rb*128 + wm*32 + mi*16 + lq*4 + j,
    //                 time = wn*64 + ni*16 + lr
    float* plds = (float*)&Ab[0][0];   // 4 x 256 floats (LDS free now)

    #pragma unroll
    for (int ni = 0; ni < 4; ++ni) {
        const int a_idx = wn * 64 + ni * 16 + lr;
        float ps = 0.f;
        #pragma unroll
        for (int mi = 0; mi < 2; ++mi) {
            const int bg = rb * 128 + wm * 32 + mi * 16 + lq * 4;
            const ushort4 w = *(const ushort4*)(obf + (size_t)a_idx * DDIM + bg);
            ps += bf2f(w.x) * acc[mi][ni][0];
            ps += bf2f(w.y) * acc[mi][ni][1];
            ps += bf2f(w.z) * acc[mi][ni][2];
            ps += bf2f(w.w) * acc[mi][ni][3];
        }
        ps += __shfl_xor(ps, 16);
        ps += __shfl_xor(ps, 32);
        if (lane < 16) plds[wm * 256 + a_idx] = ps;
    }
    __syncthreads();
    if (tid < 256)
        part[((size_t)d * 16 + rb) * TTIMES + tid] =
            plds[tid] + plds[256 + tid] + plds[512 + tid] + plds[768 + tid];
}

// ---------------- final reduce over row-blocks ----------------
__global__ void reduce_part(const float* __restrict__ part, float* __restrict__ out) {
    const int d = blockIdx.x;    // 32
    const int a = threadIdx.x;   // 256
    float s = 0.f;
    #pragma unroll
    for (int rb = 0; rb < 16; ++rb)
        s += part[((size_t)d * 16 + rb) * TTIMES + a];
    out[(size_t)d * TTIMES + a] = s;
}

extern "C" void kernel_launch(void* const* d_in, const int* in_sizes, int n_in,
                              void* d_out, int out_size, void* d_ws, size_t ws_size,
                              hipStream_t stream) {
    const float* x   = (const float*)d_in[0];   // (32, 2048, 2048) fp32
    const float* org = (const float*)d_in[1];   // (256, 2048) fp32
    float* out = (float*)d_out;                 // (32, 256) fp32

    ushort* obf = (ushort*)d_ws;                          // 1 MiB bf16 normalized o
    float*  prt = (float*)((char*)d_ws + (1 << 20));      // 512 KiB partials (32x16x256)

    norm_rows<<<dim3(TTIMES), dim3(256), 0, stream>>>(org, obf);
    gemm_trace<<<dim3(16, 32), dim3(THREADS), 0, stream>>>(x, obf, prt);
    reduce_part<<<dim3(32), dim3(256), 0, stream>>>(prt, out);
}

// Round 13
// 139.451 us; speedup vs baseline: 1.2022x; 1.2022x over previous
//
#include <hip/hip_runtime.h>
#include <hip/hip_bf16.h>

#define DDIM 2048
#define TTIMES 256
#define NT 64                 // K-steps of 32
#define THREADS 512

typedef __attribute__((ext_vector_type(8))) short short8;
typedef __attribute__((ext_vector_type(4))) float f32x4;

using gvoid = const __attribute__((address_space(1))) void;
using svoid = __attribute__((address_space(3))) void;

__device__ __forceinline__ void gld16(const void* g, void* l) {
    __builtin_amdgcn_global_load_lds((gvoid*)g, (svoid*)l, 16, 0, 0);
}

__device__ __forceinline__ ushort f2bf(float f) {
    union { float f; unsigned int u; } v; v.f = f;
    unsigned int u = v.u;
    unsigned int r = (u + 0x7FFFu + ((u >> 16) & 1u)) >> 16;   // RNE
    return (ushort)r;
}
__device__ __forceinline__ float bf2f(ushort u) {
    union { unsigned int u; float f; } v; v.u = ((unsigned int)u) << 16;
    return v.f;
}
__device__ __forceinline__ short cvt1(float f) {
    union { __hip_bfloat16 h; ushort u; } cv;
    cv.h = __float2bfloat16(f);          // hardware RNE cvt
    return (short)cv.u;
}

// ---------------- normalize org rows -> bf16 o in workspace ----------------
__global__ void norm_rows(const float* __restrict__ org, ushort* __restrict__ obf) {
    const int a   = blockIdx.x;     // time row
    const int tid = threadIdx.x;    // 256 threads
    const float* row = org + (size_t)a * DDIM;
    float4 v0 = ((const float4*)row)[tid * 2];
    float4 v1 = ((const float4*)row)[tid * 2 + 1];
    float s = v0.x*v0.x + v0.y*v0.y + v0.z*v0.z + v0.w*v0.w
            + v1.x*v1.x + v1.y*v1.y + v1.z*v1.z + v1.w*v1.w;
    #pragma unroll
    for (int off = 1; off < 64; off <<= 1) s += __shfl_xor(s, off);
    __shared__ float wsum[4];
    const int lane = tid & 63, w = tid >> 6;
    if (lane == 0) wsum[w] = s;
    __syncthreads();
    const float tot = wsum[0] + wsum[1] + wsum[2] + wsum[3];
    const float scale = 1.0f / fmaxf(sqrtf(tot), 1e-12f);
    union { ushort u[8]; uint4 v; } pk;
    pk.u[0] = f2bf(v0.x * scale); pk.u[1] = f2bf(v0.y * scale);
    pk.u[2] = f2bf(v0.z * scale); pk.u[3] = f2bf(v0.w * scale);
    pk.u[4] = f2bf(v1.x * scale); pk.u[5] = f2bf(v1.y * scale);
    pk.u[6] = f2bf(v1.z * scale); pk.u[7] = f2bf(v1.w * scale);
    ((uint4*)(obf + (size_t)a * DDIM))[tid] = pk.v;
}

// ---- BM=256 tile, (Wm=4,Wn=2), A 3-deep + B 2-deep gload_lds, 1 bar/step ----
// 256 blocks = 1/CU; LDS 128 KiB. Per step: vmcnt(4) retires A(t)+B(t),
// keeps A(t+1) (full-step HBM lead). LDS/work 31% lower than BM=128 (frag
// duplication amortized). Same verified swizzles + K-stagger as R11.
__global__ __launch_bounds__(THREADS, 2) void gemm_trace(
    const float* __restrict__ x, const ushort* __restrict__ obf,
    float* __restrict__ part)
{
    __shared__ __align__(16) char Ab[3][32768];   // fp32 A: 256 rows x 32 k
    __shared__ __align__(16) char Bb[2][16384];   // bf16 B: 256 rows x 32 k

    const int tid  = threadIdx.x;
    const int lane = tid & 63;
    const int wid  = tid >> 6;      // 0..7
    const int wm   = wid >> 1;      // 0..3 (64-row group)
    const int wn   = wid & 1;       // 0..1 (128-time half)
    const int rb   = blockIdx.x;    // 0..7 (row block of 256)
    const int d    = blockIdx.y;    // 0..31 (batch)
    const int t0   = (d * 8 + rb) & (NT - 1);   // K stagger phase
#define W(n) ((t0 + (n)) & (NT - 1))

    const char* ab = (const char*)(x + (size_t)d * DDIM * DDIM + (size_t)rb * 256 * DDIM);
    const char* bb = (const char*)obf;

    // A staging: 2048 chunks (256 rows x 8); 4 per thread; src pre-swizzled
    const int ac0 = tid,        ar0_ = ac0 >> 3, aq0 = ((ac0 & 7) ^ (ar0_ & 7)) * 16;
    const int ac1 = tid + 512,  ar1_ = ac1 >> 3, aq1 = ((ac1 & 7) ^ (ar1_ & 7)) * 16;
    const int ac2 = tid + 1024, ar2_ = ac2 >> 3, aq2 = ((ac2 & 7) ^ (ar2_ & 7)) * 16;
    const int ac3 = tid + 1536, ar3_ = ac3 >> 3, aq3 = ((ac3 & 7) ^ (ar3_ & 7)) * 16;
    const char* as0 = ab + (size_t)ar0_ * (DDIM * 4) + aq0;
    const char* as1 = ab + (size_t)ar1_ * (DDIM * 4) + aq1;
    const char* as2 = ab + (size_t)ar2_ * (DDIM * 4) + aq2;
    const char* as3 = ab + (size_t)ar3_ * (DDIM * 4) + aq3;

    // B staging: 1024 chunks (256 rows x 4); 2 per thread; src pre-swizzled
    const int bc0 = tid,       br0_ = bc0 >> 2, bq0 = ((bc0 & 3) ^ (br0_ & 3)) * 16;
    const int bc1 = tid + 512, br1_ = bc1 >> 2, bq1 = ((bc1 & 3) ^ (br1_ & 3)) * 16;
    const char* bs0 = bb + (size_t)br0_ * (DDIM * 2) + bq0;
    const char* bs1 = bb + (size_t)br1_ * (DDIM * 2) + bq1;

#define STAGE_A(t, buf) do {                                  \
    gld16(as0 + (t) * 128, &Ab[buf][ac0 * 16]);               \
    gld16(as1 + (t) * 128, &Ab[buf][ac1 * 16]);               \
    gld16(as2 + (t) * 128, &Ab[buf][ac2 * 16]);               \
    gld16(as3 + (t) * 128, &Ab[buf][ac3 * 16]);               \
} while (0)
#define STAGE_B(t, buf) do {                                  \
    gld16(bs0 + (t) * 64,  &Bb[buf][bc0 * 16]);               \
    gld16(bs1 + (t) * 64,  &Bb[buf][bc1 * 16]);               \
} while (0)

    const int lr = lane & 15;       // row-in-16 (A) / time-in-16 (B)
    const int lq = lane >> 4;       // k-quarter

    int aoff0[4], aoff1[4], boff[8];
    #pragma unroll
    for (int mi = 0; mi < 4; ++mi) {
        const int r = wm * 64 + mi * 16 + lr;
        aoff0[mi] = r * 128 + ((2 * lq)     ^ (r & 7)) * 16;
        aoff1[mi] = r * 128 + ((2 * lq + 1) ^ (r & 7)) * 16;
    }
    #pragma unroll
    for (int ni = 0; ni < 8; ++ni) {
        const int rt = wn * 128 + ni * 16 + lr;
        boff[ni] = rt * 64 + (lq ^ (rt & 3)) * 16;
    }

    f32x4 acc[4][8];
    #pragma unroll
    for (int mi = 0; mi < 4; ++mi)
        #pragma unroll
        for (int ni = 0; ni < 8; ++ni)
            acc[mi][ni] = (f32x4){0.f, 0.f, 0.f, 0.f};

#define COMPUTE(abuf, bbuf) do {                                            \
    short8 af[4], bfr[8];                                                   \
    _Pragma("unroll")                                                       \
    for (int mi = 0; mi < 4; ++mi) {                                        \
        const float4 lo = *(const float4*)&Ab[abuf][aoff0[mi]];             \
        const float4 hi = *(const float4*)&Ab[abuf][aoff1[mi]];             \
        short8 a8;                                                          \
        a8[0] = cvt1(lo.x); a8[1] = cvt1(lo.y);                             \
        a8[2] = cvt1(lo.z); a8[3] = cvt1(lo.w);                             \
        a8[4] = cvt1(hi.x); a8[5] = cvt1(hi.y);                             \
        a8[6] = cvt1(hi.z); a8[7] = cvt1(hi.w);                             \
        af[mi] = a8;                                                        \
    }                                                                       \
    _Pragma("unroll")                                                       \
    for (int ni = 0; ni < 8; ++ni)                                          \
        bfr[ni] = *(const short8*)&Bb[bbuf][boff[ni]];                      \
    _Pragma("unroll")                                                       \
    for (int mi = 0; mi < 4; ++mi)                                          \
        _Pragma("unroll")                                                   \
        for (int ni = 0; ni < 8; ++ni)                                      \
            acc[mi][ni] = __builtin_amdgcn_mfma_f32_16x16x32_bf16(          \
                af[mi], bfr[ni], acc[mi][ni], 0, 0, 0);                     \
} while (0)

#define VMW(n) do {                                                         \
    asm volatile("s_waitcnt vmcnt(" #n ")" ::: "memory");                   \
    __builtin_amdgcn_sched_barrier(0); } while (0)
#define SBAR do {                                                           \
    __builtin_amdgcn_sched_barrier(0);                                      \
    asm volatile("s_waitcnt lgkmcnt(0)" ::: "memory");                      \
    __builtin_amdgcn_s_barrier();                                           \
    __builtin_amdgcn_sched_barrier(0); } while (0)

    // ---- prologue: A(0)->0, B(0)->0, A(1)->1  (queue 4+2+4) ----
    STAGE_A(W(0), 0);
    STAGE_B(W(0), 0);
    STAGE_A(W(1), 1);

    int abf = 0;                   // t % 3 at loop top
    #pragma unroll 1
    for (int t = 0; t < NT - 1; ++t) {
        VMW(4);                    // retire A(t)+B(t); keep A(t+1) in flight
        SBAR;                      // compute(t-1) reads proven done
        STAGE_B(W(t + 1), (t + 1) & 1);
        if (t + 2 < NT) {
            int ab2 = abf + 2; if (ab2 >= 3) ab2 -= 3;
            STAGE_A(W(t + 2), ab2);
        }
        COMPUTE(abf, t & 1);
        ++abf; if (abf == 3) abf = 0;
    }
    // ---- last step t = NT-1 ----
    VMW(0);
    SBAR;
    COMPUTE(abf, (NT - 1) & 1);
    __syncthreads();

#undef W
#undef STAGE_A
#undef STAGE_B
#undef COMPUTE
#undef VMW
#undef SBAR

    // ---- fused trace epilogue ----
    // acc[mi][ni][j]: row = rb*256 + wm*64 + mi*16 + lq*4 + j,
    //                 time = wn*128 + ni*16 + lr
    float* plds = (float*)&Ab[0][0];   // 4 x 256 floats (LDS free now)

    #pragma unroll
    for (int ni = 0; ni < 8; ++ni) {
        const int a_idx = wn * 128 + ni * 16 + lr;
        float ps = 0.f;
        #pragma unroll
        for (int mi = 0; mi < 4; ++mi) {
            const int bg = rb * 256 + wm * 64 + mi * 16 + lq * 4;
            const ushort4 w = *(const ushort4*)(obf + (size_t)a_idx * DDIM + bg);
            ps += bf2f(w.x) * acc[mi][ni][0];
            ps += bf2f(w.y) * acc[mi][ni][1];
            ps += bf2f(w.z) * acc[mi][ni][2];
            ps += bf2f(w.w) * acc[mi][ni][3];
        }
        ps += __shfl_xor(ps, 16);
        ps += __shfl_xor(ps, 32);
        if (lane < 16) plds[wm * 256 + a_idx] = ps;
    }
    __syncthreads();
    if (tid < 256)
        part[((size_t)d * 8 + rb) * TTIMES + tid] =
            plds[tid] + plds[256 + tid] + plds[512 + tid] + plds[768 + tid];
}

// ---------------- final reduce over row-blocks ----------------
__global__ void reduce_part(const float* __restrict__ part, float* __restrict__ out) {
    const int d = blockIdx.x;    // 32
    const int a = threadIdx.x;   // 256
    float s = 0.f;
    #pragma unroll
    for (int rb = 0; rb < 8; ++rb)
        s += part[((size_t)d * 8 + rb) * TTIMES + a];
    out[(size_t)d * TTIMES + a] = s;
}

extern "C" void kernel_launch(void* const* d_in, const int* in_sizes, int n_in,
                              void* d_out, int out_size, void* d_ws, size_t ws_size,
                              hipStream_t stream) {
    const float* x   = (const float*)d_in[0];   // (32, 2048, 2048) fp32
    const float* org = (const float*)d_in[1];   // (256, 2048) fp32
    float* out = (float*)d_out;                 // (32, 256) fp32

    ushort* obf = (ushort*)d_ws;                          // 1 MiB bf16 normalized o
    float*  prt = (float*)((char*)d_ws + (1 << 20));      // 256 KiB partials (32x8x256)

    norm_rows<<<dim3(TTIMES), dim3(256), 0, stream>>>(org, obf);
    gemm_trace<<<dim3(8, 32), dim3(THREADS), 0, stream>>>(x, obf, prt);
    reduce_part<<<dim3(32), dim3(256), 0, stream>>>(prt, out);
}